// Round 5
// baseline (269.202 us; speedup 1.0000x reference)
//
#include <hip/hip_runtime.h>
#include <cstdint>
#include <cstddef>

// ---------------------------------------------------------------------------
// AffineModulatedLatentODEFunc — producer/consumer 8-wave version
//   kernel 0: prep — pack weights to f16; c1/c2 in 32x32x16 A-fragment order
//   kernel 1: fused, 512 thr = 8 waves, 64 samples/block:
//     phase 0: MLP (waves 0-3, f16 MFMA) -> gb in LDS; waves 4-7 load A-frags
//     pipeline (17 iters, 4 samples/group):
//       phase A: waves0-3 cin(g)              | waves4-7 c2(g-1) via 32x32 MFMA
//       phase B: waves0-3 c1(g) via 32x32 MFMA| waves4-7 cout(g-1)
//   32x32x16 MFMA halves LDS B-reads vs 16x16x32 (the round-4 bottleneck)
// ---------------------------------------------------------------------------

#define NB 32768

typedef _Float16 half8   __attribute__((ext_vector_type(8)));
typedef _Float16 half4_t __attribute__((ext_vector_type(4)));
typedef _Float16 half2_t __attribute__((ext_vector_type(2)));
typedef float    f32x4   __attribute__((ext_vector_type(4)));
typedef float    f32x16  __attribute__((ext_vector_type(16)));

__device__ __forceinline__ float fast_tanh(float x) {
  float e = __expf(2.0f * x);
  return 1.0f - __fdividef(2.0f, e + 1.0f);
}

__device__ __forceinline__ float elu_f(float v) {
  return v > 0.0f ? v : (__expf(v) - 1.0f);
}

// 3x3 "same" conv on a 4x4 tile, fully unrolled -> 100 FMAs
__device__ __forceinline__ void conv_acc(float acc[16], const float r[16], const float w[9]) {
#pragma unroll
  for (int y = 0; y < 4; ++y)
#pragma unroll
    for (int x = 0; x < 4; ++x)
#pragma unroll
      for (int ky = 0; ky < 3; ++ky) {
        int iy = y + ky - 1;
        if (iy < 0 || iy >= 4) continue;
#pragma unroll
        for (int kx = 0; kx < 3; ++kx) {
          int ix = x + kx - 1;
          if (ix < 0 || ix >= 4) continue;
          acc[y * 4 + x] += w[ky * 3 + kx] * r[iy * 4 + ix];
        }
      }
}

// ---------------------------------------------------------------------------
// prep: pack weights to f16.
//  W1f/W2f/Wgf: 16x16x32 A-fragment order (as round 4, verified)
//  c1t/c2t: 32x32x16 A-fragment order:
//    idx = ((f*2 + wtile)*64 + lane)*8 + j, f = tap*4+kb
//    oc = wtile*32 + (lane&31), ic = kb*16 + (lane>>5)*8 + j
// ---------------------------------------------------------------------------
__global__ __launch_bounds__(256) void prep_kernel(
    const float* __restrict__ W1, const float* __restrict__ W2,
    const float* __restrict__ Wg, const float* __restrict__ c1w,
    const float* __restrict__ c2w, _Float16* __restrict__ wt) {
  int idx = blockIdx.x * 256 + threadIdx.x;
  _Float16* W1f = wt;            // 4096
  _Float16* W2f = W1f + 4096;    // 16384
  _Float16* Wgf = W2f + 16384;   // 32768
  _Float16* c1t = Wgf + 32768;   // 36864
  _Float16* c2t = c1t + 36864;   // 36864
  if (idx < 4096) {
    int i = idx, j = i & 7, lane = (i >> 3) & 63, nt = i >> 9;
    int n = nt * 16 + (lane & 15), k = (lane >> 4) * 8 + j;
    W1f[i] = (_Float16)W1[k * 128 + n];
  } else if (idx < 20480) {
    int i = idx - 4096, j = i & 7, lane = (i >> 3) & 63, r = i >> 9;
    int kb = r & 3, nt = r >> 2;
    int n = nt * 16 + (lane & 15), k = kb * 32 + (lane >> 4) * 8 + j;
    W2f[i] = (_Float16)W2[k * 128 + n];
  } else if (idx < 53248) {
    int i = idx - 20480, j = i & 7, lane = (i >> 3) & 63, r = i >> 9;
    int kb = r & 3, ut = r >> 2;
    int n = ut * 16 + (lane & 15), k = kb * 32 + (lane >> 4) * 8 + j;
    Wgf[i] = (_Float16)Wg[k * 256 + n];
  } else if (idx < 90112) {
    int i = idx - 53248;
    int j = i & 7, lane = (i >> 3) & 63, ts = i >> 9;
    int wtile = ts & 1, f = ts >> 1, kb = f & 3, tap = f >> 2;
    int oc = wtile * 32 + (lane & 31);
    int ic = kb * 16 + (lane >> 5) * 8 + j;
    c1t[i] = (_Float16)c1w[(oc * 64 + ic) * 9 + tap];
  } else if (idx < 126976) {
    int i = idx - 90112;
    int j = i & 7, lane = (i >> 3) & 63, ts = i >> 9;
    int wtile = ts & 1, f = ts >> 1, kb = f & 3, tap = f >> 2;
    int oc = wtile * 32 + (lane & 31);
    int ic = kb * 16 + (lane >> 5) * 8 + j;
    c2t[i] = (_Float16)c2w[(oc * 64 + ic) * 9 + tap];
  }
}

// ---------------------------------------------------------------------------
#define ROWE 72            // halfs per padded position
#define SAMP 2592          // 36*72 halfs per sample
#define SLOT (4 * SAMP)    // 4 samples per pipeline slot (10368 halfs)
#define GRPS 16            // groups per block (4 samples each)
#define GBROW 264          // gb_lds row stride (halfs)

// mid conv layer via 32x32x16 MFMA. Wave covers 32 ocs (wtile) x 2 samples (sp).
__device__ __forceinline__ void mid32(
    const _Float16* __restrict__ src, _Float16* __restrict__ dst,
    const half8 af[36], const f32x4 cb[4],
    const _Float16* __restrict__ grow, int goff,
    int wtile, int sp, int lane) {
  const int col = lane & 31, hi = lane >> 5;
  const int px = col & 15, sw = col >> 4;
  const int py = px >> 2, pxx = px & 3;
  const int samp = sp * 2 + sw;            // 0..3 within group
  const _Float16* sbase = src + samp * SAMP;

  f32x16 acc = (f32x16)(0.0f);
#pragma unroll
  for (int tap = 0; tap < 9; ++tap) {
    const int ky = tap / 3, kx = tap % 3;
    const int row = py + ky;
    const int pos = row * 6 + pxx + kx;
    const int e = (row ^ (pos >> 2)) & 1;
#pragma unroll
    for (int kb = 0; kb < 4; ++kb) {
      const int ic0 = kb * 16 + hi * 8;
      const int off = pos * ROWE + ((((ic0 >> 5) ^ e) << 5)) + (ic0 & 31);
      half8 b = *(const half8*)(sbase + off);
      acc = __builtin_amdgcn_mfma_f32_32x32x16_f16(af[tap * 4 + kb], b, acc, 0, 0, 0);
    }
  }

  // epilogue: lane holds 16 ocs for (samp, px): rows = 8*g4 + 4*hi + r (+wtile*32)
  const int row_i = 1 + py;
  const int pos_i = row_i * 6 + 1 + pxx;
  const int e_i = (row_i ^ (pos_i >> 2)) & 1;
  _Float16* dbase = dst + samp * SAMP + pos_i * ROWE + ((wtile ^ e_i) << 5);
  const _Float16* gp = grow + samp * GBROW + goff;
#pragma unroll
  for (int g4 = 0; g4 < 4; ++g4) {
    const int ocb = 8 * g4 + 4 * hi;       // within 32-tile (0..28)
    const int oc = wtile * 32 + ocb;       // global oc 0..63
    half4_t gv = *(const half4_t*)(gp + oc);
    half4_t bv = *(const half4_t*)(gp + 128 + oc);
    half4_t o;
#pragma unroll
    for (int r = 0; r < 4; ++r)
      o[r] = (_Float16)fast_tanh((float)gv[r] * (acc[4 * g4 + r] + cb[g4][r]) + (float)bv[r]);
    *(half4_t*)(dbase + ocb) = o;
  }
}

__global__ __launch_bounds__(512, 2) void fused_kernel(
    const float* __restrict__ tt, const float* __restrict__ mu,
    const float* __restrict__ z, const _Float16* __restrict__ wt,
    const float* __restrict__ b1, const float* __restrict__ b2,
    const float* __restrict__ bg,
    const float* __restrict__ cin_w, const float* __restrict__ cin_b,
    const float* __restrict__ c1_b, const float* __restrict__ c2_b,
    const float* __restrict__ cout_w, const float* __restrict__ cout_b,
    float* __restrict__ out) {
  const int tid = threadIdx.x;
  const int lane = tid & 63;
  const int wid = tid >> 6;                // 0..7
  const bool isC2 = (wid >= 4);            // waves 4-7: c2 + cout
  const int w4 = wid & 3;
  const int wtile = w4 & 1;                // oc half (mid layers)
  const int sp = w4 >> 1;                  // sample pair (mid layers)
  const int s0 = blockIdx.x * (GRPS * 4);  // 64 samples/block

  const _Float16* W1f = wt;
  const _Float16* W2f = W1f + 4096;
  const _Float16* Wgf = W2f + 16384;
  const _Float16* c1t = Wgf + 32768;
  const _Float16* c2t = c1t + 36864;

  __shared__ __align__(16) _Float16 hp[4 * SLOT];        // 82944 B (hA0,hA1,hB0,hB1)
  __shared__ __align__(16) _Float16 gb_lds[64 * GBROW];  // 33792 B
  __shared__ __align__(16) _Float16 cwl[9 * 64];         // 1152 B

  const int m = lane & 15, q = lane >> 4, q8 = q * 8, q4 = q * 4;
  const int py16 = m >> 2, px16 = m & 3;   // for cin/cout (pixel = m)

  // ---- resident A-frags: wave's own layer, 36 coalesced b128 from global ----
  const _Float16* at = isC2 ? c2t : c1t;
  half8 af[36];
#pragma unroll
  for (int f = 0; f < 36; ++f)
    af[f] = *(const half8*)(at + ((f * 2 + wtile) << 9) + lane * 8);

  // per-layer conv biases for epilogue (16 ocs per lane)
  const float* cbsrc = isC2 ? c2_b : c1_b;
  f32x4 cbv[4];
#pragma unroll
  for (int g4 = 0; g4 < 4; ++g4)
    cbv[g4] = *(const f32x4*)(cbsrc + wtile * 32 + 8 * g4 + 4 * (lane >> 5));

  float cw9[9];
  float cinb = 0.0f;
  if (!isC2) {
#pragma unroll
    for (int t = 0; t < 9; ++t) cw9[t] = cin_w[lane * 9 + t];
    cinb = cin_b[lane];
  } else {
    // stage cout weights (separate LDS region, safe during MLP)
    for (int i = tid - 256; i < 576; i += 256) {
      if (i >= 0) {
        int ic = i / 9, tap = i % 9;
        cwl[tap * 64 + ic] = (_Float16)cout_w[i];
      }
    }
  }
  const float cob = cout_b[0];

  // ===================== Phase 0: MLP (waves 0-3) =====================
  if (!isC2) {
    const int sl = wid * 16 + m;             // block-local sample 0..63
    const int s = s0 + sl;
    _Float16* xw = hp + wid * SAMP;          // bounce scratch (pre-zero phase)

    const float TM = 31.41592653589793f;
    float base = (q == 0) ? tt[s] : mu[(size_t)s * 3 + (q - 1)];
    half8 xb;
    float fr = 1.0f;
#pragma unroll
    for (int j = 0; j < 4; ++j) {
      float sn, cs;
      __sincosf(base * fr, &sn, &cs);
      xb[j] = (_Float16)sn;
      xb[4 + j] = (_Float16)cs;
      fr *= (1.0f / TM);
    }

    // L1: h = elu(x@W1+b1)
#pragma unroll
    for (int nt = 0; nt < 8; ++nt) {
      half8 a = *(const half8*)(W1f + (nt * 64 + lane) * 8);
      f32x4 c = __builtin_amdgcn_mfma_f32_16x16x32_f16(a, xb, (f32x4)(0.0f), 0, 0, 0);
      f32x4 bv = *(const f32x4*)(b1 + nt * 16 + q4);
      half4_t o;
#pragma unroll
      for (int r = 0; r < 4; ++r) o[r] = (_Float16)elu_f(c[r] + bv[r]);
      *(half4_t*)(xw + m * 136 + nt * 16 + q4) = o;
    }
    half8 xf0 = *(const half8*)(xw + m * 136 + 0 + q8);
    half8 xf1 = *(const half8*)(xw + m * 136 + 32 + q8);
    half8 xf2 = *(const half8*)(xw + m * 136 + 64 + q8);
    half8 xf3 = *(const half8*)(xw + m * 136 + 96 + q8);

    // L2: xi = elu(h@W2+b2)
#pragma unroll
    for (int nt = 0; nt < 8; ++nt) {
      const _Float16* wp = W2f + (nt * 4) * 512 + lane * 8;
      f32x4 c = (f32x4)(0.0f);
      c = __builtin_amdgcn_mfma_f32_16x16x32_f16(*(const half8*)(wp), xf0, c, 0, 0, 0);
      c = __builtin_amdgcn_mfma_f32_16x16x32_f16(*(const half8*)(wp + 512), xf1, c, 0, 0, 0);
      c = __builtin_amdgcn_mfma_f32_16x16x32_f16(*(const half8*)(wp + 1024), xf2, c, 0, 0, 0);
      c = __builtin_amdgcn_mfma_f32_16x16x32_f16(*(const half8*)(wp + 1536), xf3, c, 0, 0, 0);
      f32x4 bv = *(const f32x4*)(b2 + nt * 16 + q4);
      half4_t o;
#pragma unroll
      for (int r = 0; r < 4; ++r) o[r] = (_Float16)elu_f(c[r] + bv[r]);
      *(half4_t*)(xw + m * 136 + nt * 16 + q4) = o;
    }
    half8 yf0 = *(const half8*)(xw + m * 136 + 0 + q8);
    half8 yf1 = *(const half8*)(xw + m * 136 + 32 + q8);
    half8 yf2 = *(const half8*)(xw + m * 136 + 64 + q8);
    half8 yf3 = *(const half8*)(xw + m * 136 + 96 + q8);

    // L3: gb = xi@Wg + bg -> gb_lds
#pragma unroll
    for (int ut = 0; ut < 16; ++ut) {
      const _Float16* wp = Wgf + (ut * 4) * 512 + lane * 8;
      f32x4 c = (f32x4)(0.0f);
      c = __builtin_amdgcn_mfma_f32_16x16x32_f16(*(const half8*)(wp), yf0, c, 0, 0, 0);
      c = __builtin_amdgcn_mfma_f32_16x16x32_f16(*(const half8*)(wp + 512), yf1, c, 0, 0, 0);
      c = __builtin_amdgcn_mfma_f32_16x16x32_f16(*(const half8*)(wp + 1024), yf2, c, 0, 0, 0);
      c = __builtin_amdgcn_mfma_f32_16x16x32_f16(*(const half8*)(wp + 1536), yf3, c, 0, 0, 0);
      f32x4 bv = *(const f32x4*)(bg + ut * 16 + q4);
      half4_t o;
#pragma unroll
      for (int r = 0; r < 4; ++r) o[r] = (_Float16)(c[r] + bv[r]);
      *(half4_t*)(gb_lds + sl * GBROW + ut * 16 + q4) = o;
    }
  }
  __syncthreads();

  // zero all h slots (borders must be 0; interiors overwritten each use)
  {
    uint32_t* hp32 = (uint32_t*)hp;
    for (int i = tid; i < (4 * SLOT) / 2; i += 512) hp32[i] = 0u;
  }
  __syncthreads();

  // ===================== Pipeline: 17 iterations =====================
  // iter it: A: cin(it) [W0] | c2(it-1): hB[(it-1)&1] -> hA[(it-1)&1] [W1]
  //          B: c1(it): hA[it&1] -> hB[it&1] [W0] | cout(it-1) [W1]
  for (int it = 0; it <= GRPS; ++it) {
    // ---------------- phase A ----------------
    if (!isC2) {
      if (it < GRPS) {
        // cin: wave w4 -> sample it*4+w4; lane = oc
        const float* zp = z + (size_t)(s0 + it * 4 + w4) * 16;
        float r[16], acc[16];
#pragma unroll
        for (int p = 0; p < 16; ++p) { r[p] = zp[p]; acc[p] = 0.0f; }
        conv_acc(acc, r, cw9);
        _Float16* dst = hp + (it & 1) * SLOT + w4 * SAMP;
        const int ics = lane & 31, ich = lane >> 5;
#pragma unroll
        for (int p = 0; p < 16; ++p) {
          int row = 1 + (p >> 2);
          int pos = row * 6 + 1 + (p & 3);
          int e = (row ^ (pos >> 2)) & 1;
          dst[pos * ROWE + ((ich ^ e) << 5) + ics] = (_Float16)fast_tanh(acc[p] + cinb);
        }
      }
    } else {
      if (it >= 1) {
        const int j = (it - 1) & 1;
        mid32(hp + (2 + j) * SLOT, hp + j * SLOT, af, cbv,
              gb_lds + (size_t)((it - 1) * 4) * GBROW, 64, wtile, sp, lane);
      }
    }
    __syncthreads();

    // ---------------- phase B ----------------
    if (!isC2) {
      if (it < GRPS) {
        const int j = it & 1;
        mid32(hp + j * SLOT, hp + (2 + j) * SLOT, af, cbv,
              gb_lds + (size_t)(it * 4) * GBROW, 0, wtile, sp, lane);
      }
    } else {
      if (it >= 1) {
        // cout: wave w4 -> sample (it-1)*4+w4; lane = (ic-quarter q, pixel m)
        const _Float16* src = hp + ((it - 1) & 1) * SLOT + w4 * SAMP;
        const int c32 = q >> 1;
        const int coff = (q * 16) & 31;
        float acc = 0.0f;
#pragma unroll
        for (int tap = 0; tap < 9; ++tap) {
          const int ky = tap / 3, kx = tap % 3;
          const int row = py16 + ky;
          const int pos = row * 6 + px16 + kx;
          const int e = (row ^ (pos >> 2)) & 1;
          const _Float16* spp = src + pos * ROWE + ((c32 ^ e) << 5) + coff;
          half8 hv0 = *(const half8*)(spp);
          half8 hv1 = *(const half8*)(spp + 8);
          half8 wv0 = *(const half8*)(cwl + tap * 64 + q * 16);
          half8 wv1 = *(const half8*)(cwl + tap * 64 + q * 16 + 8);
#pragma unroll
          for (int jj = 0; jj < 4; ++jj) {
            half2_t h2a = {hv0[2 * jj], hv0[2 * jj + 1]};
            half2_t w2a = {wv0[2 * jj], wv0[2 * jj + 1]};
            half2_t h2b = {hv1[2 * jj], hv1[2 * jj + 1]};
            half2_t w2b = {wv1[2 * jj], wv1[2 * jj + 1]};
#if __has_builtin(__builtin_amdgcn_fdot2)
            acc = __builtin_amdgcn_fdot2(h2a, w2a, acc, false);
            acc = __builtin_amdgcn_fdot2(h2b, w2b, acc, false);
#else
            acc += (float)h2a[0] * (float)w2a[0] + (float)h2a[1] * (float)w2a[1];
            acc += (float)h2b[0] * (float)w2b[0] + (float)h2b[1] * (float)w2b[1];
#endif
          }
        }
        acc += __shfl_xor(acc, 16);
        acc += __shfl_xor(acc, 32);
        if (q == 0) out[(size_t)(s0 + (it - 1) * 4 + w4) * 16 + m] = acc + cob;
      }
    }
    __syncthreads();
  }
}

// ---------------------------------------------------------------------------
extern "C" void kernel_launch(void* const* d_in, const int* in_sizes, int n_in,
                              void* d_out, int out_size, void* d_ws, size_t ws_size,
                              hipStream_t stream) {
  const float* tt     = (const float*)d_in[0];
  const float* z      = (const float*)d_in[1];
  const float* mu     = (const float*)d_in[2];
  const float* W1     = (const float*)d_in[3];
  const float* b1     = (const float*)d_in[4];
  const float* W2     = (const float*)d_in[5];
  const float* b2     = (const float*)d_in[6];
  const float* Wg     = (const float*)d_in[7];
  const float* bg     = (const float*)d_in[8];
  const float* cin_w  = (const float*)d_in[9];
  const float* cin_b  = (const float*)d_in[10];
  const float* c1_w   = (const float*)d_in[11];
  const float* c1_b   = (const float*)d_in[12];
  const float* c2_w   = (const float*)d_in[13];
  const float* c2_b   = (const float*)d_in[14];
  const float* cout_w = (const float*)d_in[15];
  const float* cout_b = (const float*)d_in[16];

  float* out = (float*)d_out;
  _Float16* wt = (_Float16*)d_ws;   // 126976 f16 packed weights

  prep_kernel<<<496, 256, 0, stream>>>(W1, W2, Wg, c1_w, c2_w, wt);
  fused_kernel<<<NB / 64, 512, 0, stream>>>(
      tt, mu, z, wt, b1, b2, bg, cin_w, cin_b, c1_b, c2_b, cout_w, cout_b, out);
}